// Round 17
// baseline (688.549 us; speedup 1.0000x reference)
//
#include <hip/hip_runtime.h>
#include <hip/hip_fp16.h>

#define TPBM 1024        // mega-kernel block (16 waves)
#define NBLK 256         // mega-kernel grid = CU count -> co-residency guaranteed
#define RNG 128          // nodes per range
#define RSH 7            // log2(RNG)
#define MAXC 1024        // max ranges supported by LDS hist (N <= 131072)
#define EPB 8192         // edges per place chunk
#define CAPR 4096        // per-range region capacity (mean ~2046, ~40 sigma)
#define CSH 12           // log2(CAPR)

// ---------------------------------------------------------------------------
// GCN, fully commuted (aggregate only at width 16), SINGLE persistent kernel:
//   phase0: Wf = W2@WL, bf = b2@WL + bL; zero gcur
//   phase1 (place): per-chunk LDS count -> one atomicAdd(&gcur[c],v) chunk
//           reservation -> chunked packed writes gbuf[c*4096+..]  (src<<7|dst&127)
//   phase2 (sort2): region -> LDS elist -> per-node sort -> bucketS region,
//           pack[n]=(exoff<<16)|deg, fp16 hsx = dinv*x
//   phase3 (l1f): nodes-in-lane gather + reg-weight GEMM16->64 + relu + proj -> z
//   phase4 (l3):  nodes-in-lane gather of z + bias -> out
// Grid barriers: per-block flag arrays, agent-scope atomics (cross-XCD safe).
// Flags need no init: harness re-poisons ws to 0xAA (!= 1) before every launch.
// 256 blocks x 1024 thr, __launch_bounds__(1024,4): 1 block/CU -> all resident.
// Replay-stable: identical per-node summation shapes to R16; no fp atomics.
// ---------------------------------------------------------------------------

__device__ inline void acc4(float a[4], uint2 u) {
    __half2 h0 = *(__half2*)&u.x, h1 = *(__half2*)&u.y;
    float2 f0 = __half22float2(h0), f1 = __half22float2(h1);
    a[0] += f0.x; a[1] += f0.y; a[2] += f1.x; a[3] += f1.y;
}

__device__ inline void gbar(int* flags) {
    __syncthreads();
    __threadfence();                               // drain data writes (device scope)
    if (threadIdx.x == 0)
        __hip_atomic_store(&flags[blockIdx.x], 1, __ATOMIC_RELEASE,
                           __HIP_MEMORY_SCOPE_AGENT);
    if (threadIdx.x < NBLK) {
        while (__hip_atomic_load(&flags[threadIdx.x], __ATOMIC_ACQUIRE,
                                 __HIP_MEMORY_SCOPE_AGENT) != 1)
            __builtin_amdgcn_s_sleep(8);
    }
    __syncthreads();
}

union SMem {
    int h[MAXC];                                   // place: 4 KB
    struct {                                       // sort2: ~18.5 KB
        unsigned elist[CAPR];
        int cnt[RNG]; int offs[RNG]; int cur[RNG]; float sdi[RNG];
    } s;
    struct __align__(16) {                         // l1f: 20 KB
        float agg[16][16][16];
        float vrow[16][64];
    } l;
};

__global__ __launch_bounds__(TPBM, 4) void
k_mega(const int* __restrict__ ei, int* __restrict__ gcur,
       unsigned* __restrict__ gbuf, int* __restrict__ bucketS,
       unsigned* __restrict__ pack,
       const float* __restrict__ x, const float* __restrict__ W1,
       const float* __restrict__ b1, const float* __restrict__ W2,
       const float* __restrict__ WL, const float* __restrict__ b2,
       const float* __restrict__ bL, float* __restrict__ Wf,
       float* __restrict__ bf, __half2* __restrict__ hsx,
       __half2* __restrict__ z, float* __restrict__ out,
       int* __restrict__ flags, int E, int C, int N, int NB) {
    __shared__ SMem sm;
    int t = threadIdx.x, b = blockIdx.x;

    // ---- phase 0: Wf/bf (block 0) + gcur zero ----
    if (b == 0) {
        int k = t >> 4, o = t & 15;                // 1024 = 64*16 exact
        float s = 0.f;
#pragma unroll 8
        for (int j = 0; j < 128; j++) s += W2[k * 128 + j] * WL[j * 16 + o];
        Wf[t] = s;
        if (t < 16) {
            float sb = bL[t];
            for (int j = 0; j < 128; j++) sb += b2[j] * WL[j * 16 + t];
            bf[t] = sb;
        }
        for (int i = t; i < C; i += TPBM) gcur[i] = 0;
    }
    gbar(flags);

    // ---- phase 1: chunked placement into per-range regions ----
    const int4* s4p = (const int4*)ei;
    const int4* d4p = (const int4*)(ei + E);
    int nq = E >> 2;
    for (int chunk = b; chunk < NB; chunk += NBLK) {
        for (int c = t; c < C; c += TPBM) sm.h[c] = 0;
        __syncthreads();
        int qbase = chunk * (EPB / 4);
#pragma unroll
        for (int it = 0; it < EPB / (4 * TPBM); it++) {   // pass 1: count
            int q = qbase + it * TPBM + t;
            if (q < nq) {
                int4 d = d4p[q];
                atomicAdd(&sm.h[d.x >> RSH], 1);
                atomicAdd(&sm.h[d.y >> RSH], 1);
                atomicAdd(&sm.h[d.z >> RSH], 1);
                atomicAdd(&sm.h[d.w >> RSH], 1);
            }
        }
        __syncthreads();
        for (int c = t; c < C; c += TPBM) {        // reserve chunk per range
            int v = sm.h[c];
            if (v) sm.h[c] = (c << CSH) + atomicAdd(&gcur[c], v);
        }
        __syncthreads();
#pragma unroll
        for (int it = 0; it < EPB / (4 * TPBM); it++) {   // pass 2: place
            int q = qbase + it * TPBM + t;
            if (q < nq) {
                int4 s = s4p[q];
                int4 d = d4p[q];
                int c0 = d.x >> RSH, c1 = d.y >> RSH, c2 = d.z >> RSH, c3 = d.w >> RSH;
                int p0 = atomicAdd(&sm.h[c0], 1);
                if (p0 < ((c0 + 1) << CSH))
                    gbuf[p0] = ((unsigned)s.x << RSH) | (unsigned)(d.x & (RNG - 1));
                int p1 = atomicAdd(&sm.h[c1], 1);
                if (p1 < ((c1 + 1) << CSH))
                    gbuf[p1] = ((unsigned)s.y << RSH) | (unsigned)(d.y & (RNG - 1));
                int p2 = atomicAdd(&sm.h[c2], 1);
                if (p2 < ((c2 + 1) << CSH))
                    gbuf[p2] = ((unsigned)s.z << RSH) | (unsigned)(d.z & (RNG - 1));
                int p3 = atomicAdd(&sm.h[c3], 1);
                if (p3 < ((c3 + 1) << CSH))
                    gbuf[p3] = ((unsigned)s.w << RSH) | (unsigned)(d.w & (RNG - 1));
            }
        }
        __syncthreads();
    }
    gbar(flags + NBLK);

    // ---- phase 2: per-range node sort -> bucketS + pack + fp16 hsx ----
    for (int r = b; r < C; r += NBLK) {
        if (t < RNG) sm.s.cnt[t] = 0;
        __syncthreads();
        int m = min(gcur[r], CAPR);
        const unsigned* src = gbuf + ((size_t)r << CSH);
        for (int i = t; i < m; i += TPBM) {
            unsigned p = src[i];
            sm.s.elist[i] = p;
            atomicAdd(&sm.s.cnt[p & (RNG - 1)], 1);
        }
        __syncthreads();
        if (t < RNG) sm.s.offs[t] = sm.s.cnt[t];
        __syncthreads();
        for (int off = 1; off < RNG; off <<= 1) {  // Hillis-Steele inclusive
            int v = 0;
            if (t < RNG && t >= off) v = sm.s.offs[t - off];
            __syncthreads();
            if (t < RNG) sm.s.offs[t] += v;
            __syncthreads();
        }
        if (t < RNG) {
            int ex = sm.s.offs[t] - sm.s.cnt[t];   // exclusive
            sm.s.cur[t] = ex;
            sm.s.sdi[t] = rsqrtf((float)sm.s.cnt[t] + 1.0f);
            int n = r * RNG + t;
            if (n < N) pack[n] = ((unsigned)ex << 16) | (unsigned)sm.s.cnt[t];
        }
        __syncthreads();
        int rbase = r << CSH;
        for (int i = t; i < m; i += TPBM) {
            unsigned p = sm.s.elist[i];
            int pos = rbase + atomicAdd(&sm.s.cur[p & (RNG - 1)], 1);
            bucketS[pos] = (int)(p >> RSH);
        }
        for (int idx = t; idx < RNG * 8; idx += TPBM) {  // hsx = fp16(dinv*x)
            int ln = idx >> 3, f2 = idx & 7;
            int n = r * RNG + ln;
            if (n < N) {
                float2 xv = ((const float2*)x)[(size_t)n * 8 + f2];
                float dn = sm.s.sdi[ln];
                hsx[(size_t)n * 8 + f2] = __floats2half2_rn(xv.x * dn, xv.y * dn);
            }
        }
        __syncthreads();                           // elist/cnt reuse next iter
    }
    gbar(flags + 2 * NBLK);

    // ---- phase 3: l1f — gather + GEMM(16->64) + relu + projection -> z ----
    {
        int wid = t >> 6, lane = t & 63;
        int part = lane >> 4, o = lane & 15;
        float w1c[16], wfc[16];
#pragma unroll
        for (int k = 0; k < 16; k++) w1c[k] = W1[k * 64 + lane];
#pragma unroll
        for (int j = 0; j < 16; j++) wfc[j] = Wf[(part * 16 + j) * 16 + o];
        float b1v = b1[lane];
        int n4 = lane >> 2, q = lane & 3;
        int NG = (N + 255) >> 8;                   // 256-node groups
        const uint2* hx = (const uint2*)hsx;
        for (int g = b; g < NG; g += NBLK) {
            int nodeG = g * 256 + wid * 16;
            int n = nodeG + n4;
            bool valid = n < N;
            int base = 0, d = 0;
            if (valid) {
                unsigned p = pack[n];
                base = ((n >> RSH) << CSH) + (int)(p >> 16);
                d = (int)(p & 0xFFFF);
            }
            float a[4] = {0.f, 0.f, 0.f, 0.f};
            if (valid) acc4(a, hx[(size_t)n * 4 + q]);      // self-loop
            int k = 0;
            for (; k + 1 < d; k += 2) {
                int s0 = bucketS[base + k];
                int s1 = bucketS[base + k + 1];
                uint2 u0 = hx[(size_t)s0 * 4 + q];
                uint2 u1 = hx[(size_t)s1 * 4 + q];
                acc4(a, u0);
                acc4(a, u1);
            }
            if (k < d) acc4(a, hx[(size_t)bucketS[base + k] * 4 + q]);
            *(float4*)&sm.l.agg[wid][n4][q * 4] = make_float4(a[0], a[1], a[2], a[3]);
            const float4* avp = (const float4*)sm.l.agg[wid];
            const float4* vrp = (const float4*)sm.l.vrow[wid];
#pragma unroll 4
            for (int nn = 0; nn < 16; nn++) {
                int node = nodeG + nn;
                if (node >= N) break;              // wave-uniform
                float dn = rsqrtf((float)__shfl(d, nn * 4) + 1.0f);
                float4 A0 = avp[nn * 4 + 0], A1 = avp[nn * 4 + 1];
                float4 A2 = avp[nn * 4 + 2], A3 = avp[nn * 4 + 3];
                float av[16] = {A0.x, A0.y, A0.z, A0.w, A1.x, A1.y, A1.z, A1.w,
                                A2.x, A2.y, A2.z, A2.w, A3.x, A3.y, A3.z, A3.w};
                float v = 0.f;
#pragma unroll
                for (int kk = 0; kk < 16; kk++) v += av[kk] * w1c[kk];
                v = fmaxf(dn * v + b1v, 0.f) * dn;
                sm.l.vrow[wid][lane] = v;          // same-wave roundtrip
                float4 V0 = vrp[part * 4 + 0], V1 = vrp[part * 4 + 1];
                float4 V2 = vrp[part * 4 + 2], V3 = vrp[part * 4 + 3];
                float vv[16] = {V0.x, V0.y, V0.z, V0.w, V1.x, V1.y, V1.z, V1.w,
                                V2.x, V2.y, V2.z, V2.w, V3.x, V3.y, V3.z, V3.w};
                float s = 0.f;
#pragma unroll
                for (int j = 0; j < 16; j++) s += vv[j] * wfc[j];
                s += __shfl_xor(s, 16);
                s += __shfl_xor(s, 32);
                float pv = __shfl(s, lane | 1);
                if (part == 0 && !(lane & 1))
                    z[(size_t)node * 8 + (o >> 1)] = __floats2half2_rn(s, pv);
            }
        }
    }
    gbar(flags + 3 * NBLK);

    // ---- phase 4: l3 — gather z + bias -> out ----
    {
        int n4 = t >> 2, q = t & 3;                // 256 nodes per block-iter
        float4 bq = ((const float4*)bf)[q];
        int NG = (N + 255) >> 8;
        const uint2* zx = (const uint2*)z;
        for (int g = b; g < NG; g += NBLK) {
            int n = g * 256 + n4;
            if (n >= N) continue;
            unsigned p = pack[n];
            int base = ((n >> RSH) << CSH) + (int)(p >> 16);
            int d = (int)(p & 0xFFFF);
            float a[4] = {0.f, 0.f, 0.f, 0.f};
            acc4(a, zx[(size_t)n * 4 + q]);        // self-loop
            int k = 0;
            for (; k + 1 < d; k += 2) {
                int s0 = bucketS[base + k];
                int s1 = bucketS[base + k + 1];
                uint2 u0 = zx[(size_t)s0 * 4 + q];
                uint2 u1 = zx[(size_t)s1 * 4 + q];
                acc4(a, u0);
                acc4(a, u1);
            }
            if (k < d) acc4(a, zx[(size_t)bucketS[base + k] * 4 + q]);
            float dn = rsqrtf((float)d + 1.0f);
            float4 r;
            r.x = dn * a[0] + bq.x;
            r.y = dn * a[1] + bq.y;
            r.z = dn * a[2] + bq.z;
            r.w = dn * a[3] + bq.w;
            ((float4*)out)[(size_t)n * 4 + q] = r; // fully coalesced
        }
    }
}

extern "C" void kernel_launch(void* const* d_in, const int* in_sizes, int n_in,
                              void* d_out, int out_size, void* d_ws, size_t ws_size,
                              hipStream_t stream) {
    const float* x  = (const float*)d_in[0];
    const int*   ei = (const int*)d_in[1];
    const float* W1 = (const float*)d_in[2];
    const float* b1 = (const float*)d_in[3];
    const float* W2 = (const float*)d_in[4];
    const float* b2 = (const float*)d_in[5];
    const float* WL = (const float*)d_in[6];
    const float* bL = (const float*)d_in[7];
    float* out = (float*)d_out;

    const int N  = in_sizes[0] / 16;       // 100000
    const int E  = in_sizes[1] / 2;        // 1600000
    const int C  = (N + RNG - 1) >> RSH;   // 782 ranges
    const int NB = (E + EPB - 1) / EPB;    // 196 place chunks

    // ws ints: gbuf[C*CAPR] | bucketS[C*CAPR] | gcur[C] | pack[N] | flags[4*256] | pad
    //    then: Wf[1024] f32 | bf[16] | pad16B | hsx[8N] half2 | z[8N] half2
    int* wsi        = (int*)d_ws;
    unsigned* gbuf  = (unsigned*)wsi;
    int* bucketS    = wsi + ((size_t)C << CSH);
    int* gcur       = bucketS + ((size_t)C << CSH);
    unsigned* pack  = (unsigned*)(gcur + C);
    int* flags      = (int*)(pack + N);            // 4*NBLK ints, poison != 1
    size_t off      = ((size_t)C << (CSH + 1)) + C + N + 4 * NBLK;
    off = (off + 3) & ~(size_t)3;
    float* Wf    = (float*)(wsi + off);
    float* bf    = Wf + 1024;
    off = off + 1024 + 16;
    off = (off + 3) & ~(size_t)3;                 // 16B-align fp16 section
    __half2* hsx = (__half2*)(wsi + off);         // 8N half2
    __half2* z   = (__half2*)(wsi + off + (size_t)8 * N);

    // single persistent kernel: all 5 phases, grid barriers between them
    k_mega<<<NBLK, TPBM, 0, stream>>>(ei, gcur, gbuf, bucketS, pack,
                                      x, W1, b1, W2, WL, b2, bL, Wf, bf,
                                      hsx, z, out, flags, E, C, N, NB);
}

// Round 18
// 151.031 us; speedup vs baseline: 4.5590x; 4.5590x over previous
//
#include <hip/hip_runtime.h>
#include <hip/hip_fp16.h>

#define TPB 256
#define TPBP 1024        // k_place block (16 waves)
#define TPBS 512         // k_sort2 block
#define RNG 128          // nodes per range
#define RSH 7            // log2(RNG)
#define MAXC 1024        // max ranges supported by LDS hist (N <= 131072)
#define EPB 8192         // edges per block in place (chunk ~10.5 edges)
#define CAPR 4096        // per-range region capacity (mean ~2046, ~40 sigma)
#define CSH 12           // log2(CAPR)

// ---------------------------------------------------------------------------
// GCN, fully commuted (aggregate only at width 16):
//   hsx = fp16(dinv*x) [N,16];  z = fp16((relu(dinv*agg@W1+b1)*dinv)@Wf) [N,16]
//   out = dinv*(z[n]+sum z[s]) + bf      (Wf = W2@WL, bf = b2@WL + bL)
// Build: fixed-capacity per-range regions (no global hist/scan):
//   place: LDS count -> one atomicAdd(&gcur[c],v) chunk reservation per
//          (block,range) -> chunked packed writes into gbuf[c*4096+..];
//          extra block NB computes Wf/bf (replaces the k_wfuse dispatch).
//   sort2: region -> LDS elist -> per-node sort -> bucketS region,
//          pack[n]=(exoff<<16)|deg, fp16 hsx. dinv recomputed from deg later.
// Aggregation: nodes-in-lane transpose gather, unroll-4 chains (R18).
// Replay-stable: fixed summation shape, no fp atomics (R9 tripwire lesson).
// R15 degree-ranked perm REVERTED (scatter-write loss); R17 persistent
// mega-kernel REVERTED (barrier straggler serialization, 4.6x regression).
// ---------------------------------------------------------------------------

__device__ inline void acc4(float a[4], uint2 u) {
    __half2 h0 = *(__half2*)&u.x, h1 = *(__half2*)&u.y;
    float2 f0 = __half22float2(h0), f1 = __half22float2(h1);
    a[0] += f0.x; a[1] += f0.y; a[2] += f1.x; a[3] += f1.y;
}

// place packed (src<<7 | dst&127) into per-range fixed regions; chunk
// reservation. Block NB (extra) instead computes Wf = W2@WL, bf = b2@WL + bL.
__global__ __launch_bounds__(TPBP) void
k_place(const int* __restrict__ ei, int* __restrict__ gcur,
        unsigned* __restrict__ gbuf,
        const float* __restrict__ W2, const float* __restrict__ WL,
        const float* __restrict__ b2, const float* __restrict__ bL,
        float* __restrict__ Wf, float* __restrict__ bf,
        int E, int C, int NB) {
    int t = threadIdx.x, b = blockIdx.x;
    if (b == NB) {                                 // fused weight-prep block
        int k = t >> 4, o = t & 15;                // t in [0,1024) = 64*16
        if (k < 64) {
            float s = 0.f;
#pragma unroll 8
            for (int j = 0; j < 128; j++) s += W2[k * 128 + j] * WL[j * 16 + o];
            Wf[t] = s;
        }
        if (t < 16) {
            float s = bL[t];
            for (int j = 0; j < 128; j++) s += b2[j] * WL[j * 16 + t];
            bf[t] = s;
        }
        return;
    }
    __shared__ int h[MAXC];
    for (int c = t; c < C; c += TPBP) h[c] = 0;
    __syncthreads();
    const int4* s4p = (const int4*)ei;
    const int4* d4p = (const int4*)(ei + E);
    int nq = E >> 2;
    int qbase = b * (EPB / 4);
#pragma unroll
    for (int it = 0; it < EPB / (4 * TPBP); it++) {  // pass 1: count
        int q = qbase + it * TPBP + t;
        if (q < nq) {
            int4 d = d4p[q];
            atomicAdd(&h[d.x >> RSH], 1);
            atomicAdd(&h[d.y >> RSH], 1);
            atomicAdd(&h[d.z >> RSH], 1);
            atomicAdd(&h[d.w >> RSH], 1);
        }
    }
    __syncthreads();
    for (int c = t; c < C; c += TPBP) {           // reserve chunk per range
        int v = h[c];
        if (v) h[c] = (c << CSH) + atomicAdd(&gcur[c], v);   // absolute cursor
    }
    __syncthreads();
#pragma unroll
    for (int it = 0; it < EPB / (4 * TPBP); it++) {  // pass 2: chunked place
        int q = qbase + it * TPBP + t;
        if (q < nq) {
            int4 s = s4p[q];
            int4 d = d4p[q];
            int c0 = d.x >> RSH, c1 = d.y >> RSH, c2 = d.z >> RSH, c3 = d.w >> RSH;
            int p0 = atomicAdd(&h[c0], 1);
            if (p0 < ((c0 + 1) << CSH))
                gbuf[p0] = ((unsigned)s.x << RSH) | (unsigned)(d.x & (RNG - 1));
            int p1 = atomicAdd(&h[c1], 1);
            if (p1 < ((c1 + 1) << CSH))
                gbuf[p1] = ((unsigned)s.y << RSH) | (unsigned)(d.y & (RNG - 1));
            int p2 = atomicAdd(&h[c2], 1);
            if (p2 < ((c2 + 1) << CSH))
                gbuf[p2] = ((unsigned)s.z << RSH) | (unsigned)(d.z & (RNG - 1));
            int p3 = atomicAdd(&h[c3], 1);
            if (p3 < ((c3 + 1) << CSH))
                gbuf[p3] = ((unsigned)s.w << RSH) | (unsigned)(d.w & (RNG - 1));
        }
    }
}

// per-range node-sort (via LDS elist) -> bucketS region + packed CSR + hsx
__global__ __launch_bounds__(TPBS) void
k_sort2(const unsigned* __restrict__ gbuf, const int* __restrict__ gcur,
        const float* __restrict__ x,
        int* __restrict__ bucketS, unsigned* __restrict__ pack,
        __half2* __restrict__ hsx, int N, int C) {
    __shared__ unsigned elist[CAPR];              // 16 KiB
    __shared__ int cnt[RNG];
    __shared__ int offs[RNG];
    __shared__ int cur[RNG];
    __shared__ float sdi[RNG];
    int t = threadIdx.x, r = blockIdx.x;
    if (t < RNG) cnt[t] = 0;
    __syncthreads();
    int m = min(gcur[r], CAPR);
    const unsigned* src = gbuf + ((size_t)r << CSH);
    for (int i = t; i < m; i += TPBS) {           // single global read of region
        unsigned p = src[i];
        elist[i] = p;
        atomicAdd(&cnt[p & (RNG - 1)], 1);
    }
    __syncthreads();
    if (t < RNG) offs[t] = cnt[t];
    __syncthreads();
    for (int off = 1; off < RNG; off <<= 1) {     // Hillis-Steele inclusive scan
        int v = 0;
        if (t < RNG && t >= off) v = offs[t - off];
        __syncthreads();
        if (t < RNG) offs[t] += v;
        __syncthreads();
    }
    if (t < RNG) {
        int ex = offs[t] - cnt[t];                // exclusive
        cur[t] = ex;
        sdi[t] = rsqrtf((float)cnt[t] + 1.0f);    // +1 self-loop
        int n = r * RNG + t;
        if (n < N) pack[n] = ((unsigned)ex << 16) | (unsigned)cnt[t];
    }
    __syncthreads();
    int rbase = r << CSH;
    for (int i = t; i < m; i += TPBS) {
        unsigned p = elist[i];
        int pos = rbase + atomicAdd(&cur[p & (RNG - 1)], 1);
        bucketS[pos] = (int)(p >> RSH);
    }
    // fused: hsx[n][:] = fp16(dinv[n] * x[n][:]) — 128 nodes x 8 half2
    for (int idx = t; idx < RNG * 8; idx += TPBS) {
        int ln = idx >> 3, f2 = idx & 7;
        int n = r * RNG + ln;
        if (n < N) {
            float2 xv = ((const float2*)x)[(size_t)n * 8 + f2];
            float dn = sdi[ln];
            hsx[(size_t)n * 8 + f2] = __floats2half2_rn(xv.x * dn, xv.y * dn);
        }
    }
}

// layer 1 + projection: nodes-in-lane gather (16 nodes/wave), register weights
__global__ void k_l1f(const int* __restrict__ bucketS, const unsigned* __restrict__ pack,
                      const uint2* __restrict__ hsx, const float* __restrict__ W1,
                      const float* __restrict__ b1, const float* __restrict__ Wf,
                      __half2* __restrict__ z, int N) {
    __shared__ __align__(16) float agg[4][16][16];   // [wave][node][feat]
    __shared__ __align__(16) float vrow[4][64];
    int t = threadIdx.x, wid = t >> 6, lane = t & 63;
    int part = lane >> 4, o = lane & 15;
    // register weights: lane j holds W1[:,j]; lane (part,o) holds Wf[part*16+j][o]
    float w1c[16], wfc[16];
#pragma unroll
    for (int k = 0; k < 16; k++) w1c[k] = W1[k * 64 + lane];
#pragma unroll
    for (int j = 0; j < 16; j++) wfc[j] = Wf[(part * 16 + j) * 16 + o];
    float b1v = b1[lane];
    int nodeG = (blockIdx.x * 4 + wid) * 16;      // 16 nodes per wave
    // gather: lane (n4,q) owns node nodeG+n4, slot q (8B of the 32B row)
    int n4 = lane >> 2, q = lane & 3;
    int n = nodeG + n4;
    bool valid = n < N;
    int base = 0, d = 0;
    if (valid) {
        unsigned p = pack[n];
        base = ((n >> RSH) << CSH) + (int)(p >> 16);
        d = (int)(p & 0xFFFF);
    }
    float a[4] = {0.f, 0.f, 0.f, 0.f};
    if (valid) acc4(a, hsx[(size_t)n * 4 + q]);   // self-loop
    int k = 0;
    for (; k + 3 < d; k += 4) {                   // 4 chains/lane (R18)
        int s0 = bucketS[base + k];
        int s1 = bucketS[base + k + 1];
        int s2 = bucketS[base + k + 2];
        int s3 = bucketS[base + k + 3];
        uint2 u0 = hsx[(size_t)s0 * 4 + q];
        uint2 u1 = hsx[(size_t)s1 * 4 + q];
        uint2 u2 = hsx[(size_t)s2 * 4 + q];
        uint2 u3 = hsx[(size_t)s3 * 4 + q];
        acc4(a, u0);
        acc4(a, u1);
        acc4(a, u2);
        acc4(a, u3);
    }
    for (; k < d; k++) acc4(a, hsx[(size_t)bucketS[base + k] * 4 + q]);
    *(float4*)&agg[wid][n4][q * 4] = make_float4(a[0], a[1], a[2], a[3]);
    // epilogue: 16 nodes batched; agg/vrow same-wave LDS roundtrips (b128)
    const float4* avp = (const float4*)agg[wid];
    const float4* vrp = (const float4*)vrow[wid];
#pragma unroll 4
    for (int nn = 0; nn < 16; nn++) {
        int node = nodeG + nn;
        if (node >= N) break;                     // wave-uniform
        float dn = rsqrtf((float)__shfl(d, nn * 4) + 1.0f);  // deg from owner lane
        float4 A0 = avp[nn * 4 + 0], A1 = avp[nn * 4 + 1];
        float4 A2 = avp[nn * 4 + 2], A3 = avp[nn * 4 + 3];
        float av[16] = {A0.x, A0.y, A0.z, A0.w, A1.x, A1.y, A1.z, A1.w,
                        A2.x, A2.y, A2.z, A2.w, A3.x, A3.y, A3.z, A3.w};
        float v = 0.f;
#pragma unroll
        for (int kk = 0; kk < 16; kk++) v += av[kk] * w1c[kk];
        v = fmaxf(dn * v + b1v, 0.f) * dn;        // lane j holds v_j
        vrow[wid][lane] = v;
        float4 V0 = vrp[part * 4 + 0], V1 = vrp[part * 4 + 1];
        float4 V2 = vrp[part * 4 + 2], V3 = vrp[part * 4 + 3];
        float vv[16] = {V0.x, V0.y, V0.z, V0.w, V1.x, V1.y, V1.z, V1.w,
                        V2.x, V2.y, V2.z, V2.w, V3.x, V3.y, V3.z, V3.w};
        float s = 0.f;
#pragma unroll
        for (int j = 0; j < 16; j++) s += vv[j] * wfc[j];
        s += __shfl_xor(s, 16);
        s += __shfl_xor(s, 32);                   // all lanes: z_o, o=lane&15
        float pv = __shfl(s, lane | 1);
        if (part == 0 && !(lane & 1))
            z[(size_t)node * 8 + (o >> 1)] = __floats2half2_rn(s, pv);
    }
}

// layer 2 aggregation of z + bias: pure nodes-in-lane gather, zero DS ops
__global__ void k_l3(const int* __restrict__ bucketS, const unsigned* __restrict__ pack,
                     const uint2* __restrict__ z, const float* __restrict__ bfv,
                     float* __restrict__ out, int N) {
    int t = threadIdx.x, wid = t >> 6, lane = t & 63;
    int n4 = lane >> 2, q = lane & 3;
    int n = (blockIdx.x * 4 + wid) * 16 + n4;
    if (n >= N) return;
    float4 bq = ((const float4*)bfv)[q];
    unsigned p = pack[n];
    int base = ((n >> RSH) << CSH) + (int)(p >> 16);
    int d = (int)(p & 0xFFFF);
    float a[4] = {0.f, 0.f, 0.f, 0.f};
    acc4(a, z[(size_t)n * 4 + q]);                // self-loop
    int k = 0;
    for (; k + 3 < d; k += 4) {                   // 4 chains/lane (R18)
        int s0 = bucketS[base + k];
        int s1 = bucketS[base + k + 1];
        int s2 = bucketS[base + k + 2];
        int s3 = bucketS[base + k + 3];
        uint2 u0 = z[(size_t)s0 * 4 + q];
        uint2 u1 = z[(size_t)s1 * 4 + q];
        uint2 u2 = z[(size_t)s2 * 4 + q];
        uint2 u3 = z[(size_t)s3 * 4 + q];
        acc4(a, u0);
        acc4(a, u1);
        acc4(a, u2);
        acc4(a, u3);
    }
    for (; k < d; k++) acc4(a, z[(size_t)bucketS[base + k] * 4 + q]);
    float dn = rsqrtf((float)d + 1.0f);
    float4 r;
    r.x = dn * a[0] + bq.x;
    r.y = dn * a[1] + bq.y;
    r.z = dn * a[2] + bq.z;
    r.w = dn * a[3] + bq.w;
    ((float4*)out)[(size_t)n * 4 + q] = r;        // fully coalesced
}

extern "C" void kernel_launch(void* const* d_in, const int* in_sizes, int n_in,
                              void* d_out, int out_size, void* d_ws, size_t ws_size,
                              hipStream_t stream) {
    const float* x  = (const float*)d_in[0];
    const int*   ei = (const int*)d_in[1];
    const float* W1 = (const float*)d_in[2];
    const float* b1 = (const float*)d_in[3];
    const float* W2 = (const float*)d_in[4];
    const float* b2 = (const float*)d_in[5];
    const float* WL = (const float*)d_in[6];
    const float* bL = (const float*)d_in[7];
    float* out = (float*)d_out;

    const int N  = in_sizes[0] / 16;       // 100000
    const int E  = in_sizes[1] / 2;        // 1600000
    const int C  = (N + RNG - 1) >> RSH;   // 782 ranges
    const int NB = (E + EPB - 1) / EPB;    // 196 place blocks

    // ws ints: gbuf[C*CAPR] | bucketS[C*CAPR] | gcur[C] | pack[N] | pad
    //    then: Wf[1024] f32 | bf[16] | pad16B | hsx[8N] half2 | z[8N] half2
    int* wsi        = (int*)d_ws;
    unsigned* gbuf  = (unsigned*)wsi;
    int* bucketS    = wsi + ((size_t)C << CSH);
    int* gcur       = bucketS + ((size_t)C << CSH);
    unsigned* pack  = (unsigned*)(gcur + C);
    size_t off      = ((size_t)C << (CSH + 1)) + C + N;
    off = (off + 3) & ~(size_t)3;
    float* Wf    = (float*)(wsi + off);
    float* bf    = Wf + 1024;
    off = off + 1024 + 16;
    off = (off + 3) & ~(size_t)3;                 // 16B-align fp16 section
    __half2* hsx = (__half2*)(wsi + off);         // 8N half2
    __half2* z   = (__half2*)(wsi + off + (size_t)8 * N);

    // zero reservation cursors (3 KB) — replaces the k_wfuse dispatch
    hipMemsetAsync(gcur, 0, (size_t)C * 4, stream);

    // ---- chunked placement into per-range regions + fused Wf/bf block ----
    k_place<<<NB + 1, TPBP, 0, stream>>>(ei, gcur, gbuf, W2, WL, b2, bL, Wf, bf, E, C, NB);

    // ---- per-range node sort -> region CSR + pack + fp16 hsx ----
    k_sort2<<<C, TPBS, 0, stream>>>(gbuf, gcur, x, bucketS, pack, hsx, N, C);

    // ---- layer 1 + projection -> z fp16 [N,16] ----
    const int NBLK = (N + 63) / 64;               // 64 nodes per block (16/wave)
    k_l1f<<<NBLK, TPB, 0, stream>>>(bucketS, pack, (const uint2*)hsx, W1, b1, Wf, z, N);

    // ---- layer 2 aggregation + bias -> out ----
    k_l3<<<NBLK, TPB, 0, stream>>>(bucketS, pack, (const uint2*)z, bf, out, N);
}